// Round 1
// baseline (13166.940 us; speedup 1.0000x reference)
//
#include <hip/hip_runtime.h>
#include <math.h>

#define TSTEPS 1024
#define BATCH  512
#define HID    64
#define VOC    29
#define G4     256
#define SOS    27
#define ENC_BLOCKS  256
#define ENC_THREADS 512
#define DEC_BLOCKS  128
#define DEC_THREADS 512

__device__ __forceinline__ float sigmf(float x){ return 1.0f/(1.0f+expf(-x)); }

// ---------------- Encoder: 2-layer LSTM, batch-parallel, 2 rows/block ----------------
__global__ __launch_bounds__(ENC_THREADS, 2)
void enc_kernel(const float* __restrict__ x,
                const float* __restrict__ Wih0, const float* __restrict__ Whh0,
                const float* __restrict__ bih0, const float* __restrict__ bhh0,
                const float* __restrict__ Wih1, const float* __restrict__ Whh1,
                const float* __restrict__ bih1, const float* __restrict__ bhh1,
                float* __restrict__ h1g, float* __restrict__ c1g)
{
  const int tid = threadIdx.x;
  const int r   = tid & 255;   // gate row 0..255
  const int bl  = tid >> 8;    // local batch 0/1
  const int b0  = blockIdx.x * 2;

  __shared__ __align__(16) float w0s[G4][VOC];            // Wih0 in LDS (29 floats/row)
  __shared__ __align__(16) float xs[2][32];
  __shared__ __align__(16) float g0[2][G4];
  __shared__ __align__(16) float h0s[2][HID], c0s[2][HID], h1s[2][HID], c1s[2][HID];

  for (int i = tid; i < G4*VOC; i += ENC_THREADS) ((float*)w0s)[i] = Wih0[i];

  // per-thread recurrent weight rows (registers)
  float wh0[HID], wi1[HID], wh1[HID];
  #pragma unroll
  for (int k=0;k<HID;k++){
    wh0[k]=Whh0[r*HID+k];
    wi1[k]=Wih1[r*HID+k];
    wh1[k]=Whh1[r*HID+k];
  }
  const float bias0 = bih0[r]+bhh0[r];
  const float bias1 = bih1[r]+bhh1[r];

  if (tid<128){ int b=tid>>6,k=tid&63; h0s[b][k]=0.f;c0s[b][k]=0.f;h1s[b][k]=0.f;c1s[b][k]=0.f; }

  const int xb = tid / VOC, xk = tid - xb*VOC;  // valid for tid < 58
  float xreg = 0.f;
  if (tid < 2*VOC) xreg = x[(size_t)(b0+xb)*VOC + xk];   // t = 0

  __syncthreads();

  for (int t=0;t<TSTEPS;t++){
    if (tid < 2*VOC) xs[xb][xk] = xreg;
    __syncthreads();
    if (tid < 2*VOC && t+1 < TSTEPS)
      xreg = x[(size_t)(t+1)*BATCH*VOC + (size_t)(b0+xb)*VOC + xk];  // prefetch, used next iter

    // layer0 gates: x-dot (Wih0 from LDS) + h-dot (registers)
    {
      float acc = bias0;
      const float4* xv = (const float4*)xs[bl];
      #pragma unroll
      for (int c=0;c<7;c++){
        float4 q = xv[c];
        acc += q.x*w0s[r][4*c+0] + q.y*w0s[r][4*c+1] + q.z*w0s[r][4*c+2] + q.w*w0s[r][4*c+3];
      }
      acc += xs[bl][28]*w0s[r][28];
      const float4* hv = (const float4*)h0s[bl];
      #pragma unroll
      for (int c=0;c<16;c++){
        float4 q = hv[c];
        acc += q.x*wh0[4*c+0] + q.y*wh0[4*c+1] + q.z*wh0[4*c+2] + q.w*wh0[4*c+3];
      }
      g0[bl][r] = acc;
    }
    __syncthreads();
    if (tid<128){
      int b=tid>>6,k=tid&63;
      float ig=g0[b][k], fg=g0[b][64+k], gg=g0[b][128+k], og=g0[b][192+k];
      float c = sigmf(fg)*c0s[b][k] + sigmf(ig)*tanhf(gg);
      c0s[b][k]=c;
      h0s[b][k]=sigmf(og)*tanhf(c);
    }
    __syncthreads();
    // layer1 gates
    {
      float acc = bias1;
      const float4* av = (const float4*)h0s[bl];
      const float4* bv = (const float4*)h1s[bl];
      #pragma unroll
      for (int c=0;c<16;c++){
        float4 q = av[c], p = bv[c];
        acc += q.x*wi1[4*c+0] + q.y*wi1[4*c+1] + q.z*wi1[4*c+2] + q.w*wi1[4*c+3];
        acc += p.x*wh1[4*c+0] + p.y*wh1[4*c+1] + p.z*wh1[4*c+2] + p.w*wh1[4*c+3];
      }
      g0[bl][r] = acc;
    }
    __syncthreads();
    if (tid<128){
      int b=tid>>6,k=tid&63;
      float ig=g0[b][k], fg=g0[b][64+k], gg=g0[b][128+k], og=g0[b][192+k];
      float c = sigmf(fg)*c1s[b][k] + sigmf(ig)*tanhf(gg);
      c1s[b][k]=c;
      h1s[b][k]=sigmf(og)*tanhf(c);
    }
    __syncthreads();
  }

  if (tid<128){
    int b=tid>>6,k=tid&63;
    h1g[(b0+b)*HID+k]=h1s[b][k];
    c1g[(b0+b)*HID+k]=c1s[b][k];
  }
}

// ---------------- Decoder: cooperative, union-mask barrier per step ----------------
__global__ __launch_bounds__(DEC_THREADS, 2)
void dec_kernel(const float* __restrict__ h1gp, const float* __restrict__ c1gp,
                const float* __restrict__ W1ih, const float* __restrict__ W1hh,
                const float* __restrict__ b1ih, const float* __restrict__ b1hh,
                const float* __restrict__ W2ih, const float* __restrict__ W2hh,
                const float* __restrict__ b2ih, const float* __restrict__ b2hh,
                const float* __restrict__ clsW, const float* __restrict__ clsb,
                float* __restrict__ out,
                unsigned* __restrict__ gmask, unsigned* __restrict__ gcnt)
{
  const int tid  = threadIdx.x;
  const int r    = tid & 255;
  const int half = tid >> 8;
  const int b0   = blockIdx.x * 4;

  __shared__ __align__(16) float w1ih_s[G4][VOC];     // d1_Wih
  __shared__ __align__(16) float clsW_s[VOC][68];     // padded: 68*4B=272B rows, 16B aligned
  __shared__ __align__(16) float clsb_s[32];
  __shared__ __align__(16) float inp[G4];             // shared input-vector (same for all rows)
  __shared__ __align__(16) float gl[4][G4];
  __shared__ __align__(16) float h1s[4][HID], c1s[4][HID], h2s[4][HID], c2s[4][HID];
  __shared__ __align__(16) float pred_s[4][32];
  __shared__ unsigned bm;
  __shared__ unsigned maskLDS;

  for (int i=tid;i<G4*VOC;i+=DEC_THREADS) ((float*)w1ih_s)[i] = W1ih[i];
  for (int i=tid;i<VOC*HID;i+=DEC_THREADS) clsW_s[i/HID][i%HID] = clsW[i];
  if (tid<VOC) clsb_s[tid]=clsb[tid];

  float w1hh[HID], w2ih[HID], w2hh[HID];
  #pragma unroll
  for (int k=0;k<HID;k++){
    w1hh[k]=W1hh[r*HID+k];
    w2ih[k]=W2ih[r*HID+k];
    w2hh[k]=W2hh[r*HID+k];
  }
  const float bias1v = (tid<G4)? (b1ih[tid]+b1hh[tid]) : 0.f;
  const float bias2  = b2ih[r]+b2hh[r];

  if (tid<256){
    int b=tid>>6,k=tid&63;
    h1s[b][k]=h1gp[(b0+b)*HID+k];
    c1s[b][k]=c1gp[(b0+b)*HID+k];
    h2s[b][k]=0.f; c2s[b][k]=0.f;
  }

  unsigned mask  = 1u<<SOS;       // let0: one-hot at SOS for all rows
  unsigned built = 0xFFFFFFFFu;   // force build at s=0
  __syncthreads();

  for (int s=0;s<TSTEPS;s++){
    if (mask != built){           // block-uniform branch
      if (tid<G4){
        float vv = bias1v;
        #pragma unroll
        for (int c=0;c<VOC;c++)
          vv += (mask & (1u<<c)) ? w1ih_s[tid][c] : 0.f;
        inp[tid]=vv;
      }
      built = mask;
      __syncthreads();
    }
    if (tid==DEC_THREADS-1) bm = 0u;   // ordered before argmax by the syncs below

    // cell1 gates (input term shared, h-term per row)
    #pragma unroll
    for (int u=0;u<2;u++){
      const int b = half*2+u;
      float acc = inp[r];
      const float4* hv=(const float4*)h1s[b];
      #pragma unroll
      for (int c=0;c<16;c++){
        float4 q=hv[c];
        acc += q.x*w1hh[4*c+0]+q.y*w1hh[4*c+1]+q.z*w1hh[4*c+2]+q.w*w1hh[4*c+3];
      }
      gl[b][r]=acc;
    }
    __syncthreads();
    if (tid<256){
      int b=tid>>6,k=tid&63;
      float ig=gl[b][k],fg=gl[b][64+k],gg=gl[b][128+k],og=gl[b][192+k];
      float c=sigmf(fg)*c1s[b][k]+sigmf(ig)*tanhf(gg);
      c1s[b][k]=c; h1s[b][k]=sigmf(og)*tanhf(c);
    }
    __syncthreads();
    // cell2 gates
    #pragma unroll
    for (int u=0;u<2;u++){
      const int b=half*2+u;
      float acc=bias2;
      const float4* av=(const float4*)h1s[b];
      const float4* bv=(const float4*)h2s[b];
      #pragma unroll
      for (int c=0;c<16;c++){
        float4 q=av[c],p=bv[c];
        acc += q.x*w2ih[4*c+0]+q.y*w2ih[4*c+1]+q.z*w2ih[4*c+2]+q.w*w2ih[4*c+3];
        acc += p.x*w2hh[4*c+0]+p.y*w2hh[4*c+1]+p.z*w2hh[4*c+2]+p.w*w2hh[4*c+3];
      }
      gl[b][r]=acc;
    }
    __syncthreads();
    if (tid<256){
      int b=tid>>6,k=tid&63;
      float ig=gl[b][k],fg=gl[b][64+k],gg=gl[b][128+k],og=gl[b][192+k];
      float c=sigmf(fg)*c2s[b][k]+sigmf(ig)*tanhf(gg);
      c2s[b][k]=c; h2s[b][k]=sigmf(og)*tanhf(c);
    }
    __syncthreads();
    // classifier + output store
    if (tid < 4*VOC){
      int b=tid/VOC, v=tid-b*VOC;
      float p = clsb_s[v];
      const float4* hv=(const float4*)h2s[b];
      #pragma unroll
      for (int c=0;c<16;c++){
        float4 q=hv[c];
        p += q.x*clsW_s[v][4*c+0]+q.y*clsW_s[v][4*c+1]+q.z*clsW_s[v][4*c+2]+q.w*clsW_s[v][4*c+3];
      }
      pred_s[b][v]=p;
      out[((size_t)s*BATCH + (size_t)(b0+b))*VOC + v]=p;
    }
    __syncthreads();
    // per-row argmax (first-index tie-break), one wave per row
    if (tid<256){
      int w=tid>>6, lane=tid&63;
      float v = (lane<VOC)? pred_s[w][lane] : -INFINITY;
      int idx = lane;
      #pragma unroll
      for (int off=32; off>0; off>>=1){
        float ov=__shfl_down(v,off);
        int oi=__shfl_down(idx,off);
        if (ov>v || (ov==v && oi<idx)){ v=ov; idx=oi; }
      }
      if (lane==0) atomicOr(&bm, 1u<<idx);
    }
    __syncthreads();
    // global union-mask barrier (skip after last step)
    if (s+1<TSTEPS){
      if (tid==0){
        unsigned mb = bm;
        __hip_atomic_fetch_or(&gmask[s], mb, __ATOMIC_RELEASE, __HIP_MEMORY_SCOPE_AGENT);
        __hip_atomic_fetch_add(&gcnt[s], 1u, __ATOMIC_RELEASE, __HIP_MEMORY_SCOPE_AGENT);
        unsigned c;
        do {
          __builtin_amdgcn_s_sleep(1);
          c = __hip_atomic_load(&gcnt[s], __ATOMIC_ACQUIRE, __HIP_MEMORY_SCOPE_AGENT);
        } while (c < (unsigned)DEC_BLOCKS);
        maskLDS = __hip_atomic_load(&gmask[s], __ATOMIC_RELAXED, __HIP_MEMORY_SCOPE_AGENT);
      }
      __syncthreads();
      mask = maskLDS;
    }
  }
}

extern "C" void kernel_launch(void* const* d_in, const int* in_sizes, int n_in,
                              void* d_out, int out_size, void* d_ws, size_t ws_size,
                              hipStream_t stream)
{
  const float* x     = (const float*)d_in[0];
  const float* eWih0 = (const float*)d_in[1];
  const float* eWhh0 = (const float*)d_in[2];
  const float* ebih0 = (const float*)d_in[3];
  const float* ebhh0 = (const float*)d_in[4];
  const float* eWih1 = (const float*)d_in[5];
  const float* eWhh1 = (const float*)d_in[6];
  const float* ebih1 = (const float*)d_in[7];
  const float* ebhh1 = (const float*)d_in[8];
  const float* d1Wih = (const float*)d_in[9];
  const float* d1Whh = (const float*)d_in[10];
  const float* d1bih = (const float*)d_in[11];
  const float* d1bhh = (const float*)d_in[12];
  const float* d2Wih = (const float*)d_in[13];
  const float* d2Whh = (const float*)d_in[14];
  const float* d2bih = (const float*)d_in[15];
  const float* d2bhh = (const float*)d_in[16];
  const float* clsW  = (const float*)d_in[17];
  const float* clsb  = (const float*)d_in[18];
  float* out = (float*)d_out;

  float* h1g = (float*)d_ws;
  float* c1g = h1g + BATCH*HID;
  unsigned* gmask = (unsigned*)(c1g + BATCH*HID);
  unsigned* gcnt  = gmask + TSTEPS;

  // zero the per-step union-mask words and arrival counters (ws is poisoned each call)
  hipMemsetAsync(gmask, 0, 2*TSTEPS*sizeof(unsigned), stream);

  enc_kernel<<<ENC_BLOCKS, ENC_THREADS, 0, stream>>>(
      x, eWih0,eWhh0,ebih0,ebhh0, eWih1,eWhh1,ebih1,ebhh1, h1g,c1g);

  void* args[] = { (void*)&h1g, (void*)&c1g,
                   (void*)&d1Wih,(void*)&d1Whh,(void*)&d1bih,(void*)&d1bhh,
                   (void*)&d2Wih,(void*)&d2Whh,(void*)&d2bih,(void*)&d2bhh,
                   (void*)&clsW,(void*)&clsb,(void*)&out,(void*)&gmask,(void*)&gcnt };
  hipLaunchCooperativeKernel((void*)dec_kernel, dim3(DEC_BLOCKS), dim3(DEC_THREADS),
                             args, 0, stream);
}

// Round 2
// 9613.554 us; speedup vs baseline: 1.3696x; 1.3696x over previous
//
#include <hip/hip_runtime.h>
#include <math.h>

#define TSTEPS 1024
#define BATCH  512
#define HID    64
#define VOC    29
#define G4     256
#define SOS    27
#define ENC_BLOCKS  256
#define ENC_THREADS 512
#define DEC_BLOCKS  128
#define DEC_THREADS 512

__device__ __forceinline__ float frcp(float x){ return __builtin_amdgcn_rcpf(x); }
__device__ __forceinline__ float sigmf(float x){ return frcp(1.0f + __expf(-x)); }
__device__ __forceinline__ float tanhfast(float x){ return 1.0f - 2.0f*frcp(1.0f + __expf(2.0f*x)); }

// ---------------- Encoder: 2-layer LSTM, batch-parallel, 2 rows/block ----------------
__global__ __launch_bounds__(ENC_THREADS, 2)
void enc_kernel(const float* __restrict__ x,
                const float* __restrict__ Wih0, const float* __restrict__ Whh0,
                const float* __restrict__ bih0, const float* __restrict__ bhh0,
                const float* __restrict__ Wih1, const float* __restrict__ Whh1,
                const float* __restrict__ bih1, const float* __restrict__ bhh1,
                float* __restrict__ h1g, float* __restrict__ c1g)
{
  const int tid = threadIdx.x;
  const int r   = tid & 255;   // gate row 0..255
  const int bl  = tid >> 8;    // local batch 0/1
  const int b0  = blockIdx.x * 2;

  __shared__ __align__(16) float w0s[G4][VOC];
  __shared__ __align__(16) float xs[2][32];
  __shared__ __align__(16) float g0[2][G4];
  __shared__ __align__(16) float h0s[2][HID], c0s[2][HID], h1s[2][HID], c1s[2][HID];

  for (int i = tid; i < G4*VOC; i += ENC_THREADS) ((float*)w0s)[i] = Wih0[i];

  float wh0[HID], wi1[HID], wh1[HID];
  #pragma unroll
  for (int k=0;k<HID;k++){
    wh0[k]=Whh0[r*HID+k];
    wi1[k]=Wih1[r*HID+k];
    wh1[k]=Whh1[r*HID+k];
  }
  const float bias0 = bih0[r]+bhh0[r];
  const float bias1 = bih1[r]+bhh1[r];

  if (tid<128){ int b=tid>>6,k=tid&63; h0s[b][k]=0.f;c0s[b][k]=0.f;h1s[b][k]=0.f;c1s[b][k]=0.f; }

  const int xb = tid / VOC, xk = tid - xb*VOC;  // valid for tid < 58
  if (tid < 2*VOC) xs[xb][xk] = x[(size_t)(b0+xb)*VOC + xk];   // t = 0
  __syncthreads();

  for (int t=0;t<TSTEPS;t++){
    // prefetch next timestep's input (latency hidden across gates0/act0/gates1)
    float xn = 0.f;
    if (tid < 2*VOC && t+1 < TSTEPS)
      xn = x[(size_t)(t+1)*BATCH*VOC + (size_t)(b0+xb)*VOC + xk];

    // layer0 gates: 4 independent accumulators to break the FMA dep chain
    {
      float a0=bias0, a1=0.f, a2=0.f, a3=0.f;
      const float4* xv = (const float4*)xs[bl];
      const float*  w0 = w0s[r];
      #pragma unroll
      for (int c=0;c<7;c++){
        float4 q = xv[c];
        a0 = fmaf(q.x, w0[4*c+0], a0);
        a1 = fmaf(q.y, w0[4*c+1], a1);
        a2 = fmaf(q.z, w0[4*c+2], a2);
        a3 = fmaf(q.w, w0[4*c+3], a3);
      }
      a0 = fmaf(xs[bl][28], w0[28], a0);
      const float4* hv = (const float4*)h0s[bl];
      #pragma unroll
      for (int c=0;c<16;c++){
        float4 q = hv[c];
        a0 = fmaf(q.x, wh0[4*c+0], a0);
        a1 = fmaf(q.y, wh0[4*c+1], a1);
        a2 = fmaf(q.z, wh0[4*c+2], a2);
        a3 = fmaf(q.w, wh0[4*c+3], a3);
      }
      g0[bl][r] = (a0+a1)+(a2+a3);
    }
    __syncthreads();
    if (tid<128){
      int b=tid>>6,k=tid&63;
      float ig=g0[b][k], fg=g0[b][64+k], gg=g0[b][128+k], og=g0[b][192+k];
      float c = sigmf(fg)*c0s[b][k] + sigmf(ig)*tanhfast(gg);
      c0s[b][k]=c;
      h0s[b][k]=sigmf(og)*tanhfast(c);
    }
    __syncthreads();
    // layer1 gates
    {
      float a0=bias1, a1=0.f, a2=0.f, a3=0.f;
      const float4* av = (const float4*)h0s[bl];
      const float4* bv = (const float4*)h1s[bl];
      #pragma unroll
      for (int c=0;c<16;c++){
        float4 q = av[c], p = bv[c];
        a0 = fmaf(q.x, wi1[4*c+0], a0);
        a1 = fmaf(q.y, wi1[4*c+1], a1);
        a2 = fmaf(q.z, wi1[4*c+2], a2);
        a3 = fmaf(q.w, wi1[4*c+3], a3);
        a0 = fmaf(p.x, wh1[4*c+0], a0);
        a1 = fmaf(p.y, wh1[4*c+1], a1);
        a2 = fmaf(p.z, wh1[4*c+2], a2);
        a3 = fmaf(p.w, wh1[4*c+3], a3);
      }
      g0[bl][r] = (a0+a1)+(a2+a3);
    }
    __syncthreads();
    if (tid<128){
      int b=tid>>6,k=tid&63;
      float ig=g0[b][k], fg=g0[b][64+k], gg=g0[b][128+k], og=g0[b][192+k];
      float c = sigmf(fg)*c1s[b][k] + sigmf(ig)*tanhfast(gg);
      c1s[b][k]=c;
      h1s[b][k]=sigmf(og)*tanhfast(c);
    }
    if (tid < 2*VOC && t+1 < TSTEPS) xs[xb][xk] = xn;  // consumed after sync below
    __syncthreads();
  }

  if (tid<128){
    int b=tid>>6,k=tid&63;
    h1g[(b0+b)*HID+k]=h1s[b][k];
    c1g[(b0+b)*HID+k]=c1s[b][k];
  }
}

// ---------------- Decoder: cooperative, single-RMW tree barrier per step ----------------
__global__ __launch_bounds__(DEC_THREADS, 2)
void dec_kernel(const float* __restrict__ h1gp, const float* __restrict__ c1gp,
                const float* __restrict__ W1ih, const float* __restrict__ W1hh,
                const float* __restrict__ b1ih, const float* __restrict__ b1hh,
                const float* __restrict__ W2ih, const float* __restrict__ W2hh,
                const float* __restrict__ b2ih, const float* __restrict__ b2hh,
                const float* __restrict__ clsW, const float* __restrict__ clsb,
                float* __restrict__ out,
                unsigned long long* __restrict__ lvl1,
                unsigned long long* __restrict__ lvl2,
                unsigned* __restrict__ bc)
{
  const int tid  = threadIdx.x;
  const int r    = tid & 255;
  const int half = tid >> 8;
  const int b0   = blockIdx.x * 4;
  const unsigned grp = blockIdx.x >> 5;   // 0..3 (32 blocks each)
  const unsigned idx = blockIdx.x & 31;

  __shared__ __align__(16) float w1ih_s[G4][VOC];
  __shared__ __align__(16) float clsW_s[VOC][68];
  __shared__ __align__(16) float clsb_s[32];
  __shared__ __align__(16) float inp[G4];
  __shared__ __align__(16) float gl[4][G4];
  __shared__ __align__(16) float h1s[4][HID], c1s[4][HID], h2s[4][HID], c2s[4][HID];
  __shared__ __align__(16) float pred_s[4][32];
  __shared__ unsigned bm;
  __shared__ unsigned maskLDS;

  for (int i=tid;i<G4*VOC;i+=DEC_THREADS) ((float*)w1ih_s)[i] = W1ih[i];
  for (int i=tid;i<VOC*HID;i+=DEC_THREADS) clsW_s[i/HID][i%HID] = clsW[i];
  if (tid<VOC) clsb_s[tid]=clsb[tid];

  float w1hh[HID], w2ih[HID], w2hh[HID];
  #pragma unroll
  for (int k=0;k<HID;k++){
    w1hh[k]=W1hh[r*HID+k];
    w2ih[k]=W2ih[r*HID+k];
    w2hh[k]=W2hh[r*HID+k];
  }
  const float bias1v = (tid<G4)? (b1ih[tid]+b1hh[tid]) : 0.f;
  const float bias2  = b2ih[r]+b2hh[r];

  if (tid<256){
    int b=tid>>6,k=tid&63;
    h1s[b][k]=h1gp[(b0+b)*HID+k];
    c1s[b][k]=c1gp[(b0+b)*HID+k];
    h2s[b][k]=0.f; c2s[b][k]=0.f;
  }

  unsigned mask  = 1u<<SOS;
  unsigned built = 0xFFFFFFFFu;
  __syncthreads();

  for (int s=0;s<TSTEPS;s++){
    if (mask != built){           // block-uniform branch
      if (tid<G4){
        float vv = bias1v;
        #pragma unroll
        for (int c=0;c<VOC;c++)
          vv += (mask & (1u<<c)) ? w1ih_s[tid][c] : 0.f;
        inp[tid]=vv;
      }
      built = mask;
      __syncthreads();
    }
    if (tid==DEC_THREADS-1) bm = 0u;

    // cell1 gates
    #pragma unroll
    for (int u=0;u<2;u++){
      const int b = half*2+u;
      float a0=inp[r], a1=0.f, a2=0.f, a3=0.f;
      const float4* hv=(const float4*)h1s[b];
      #pragma unroll
      for (int c=0;c<16;c++){
        float4 q=hv[c];
        a0 = fmaf(q.x, w1hh[4*c+0], a0);
        a1 = fmaf(q.y, w1hh[4*c+1], a1);
        a2 = fmaf(q.z, w1hh[4*c+2], a2);
        a3 = fmaf(q.w, w1hh[4*c+3], a3);
      }
      gl[b][r]=(a0+a1)+(a2+a3);
    }
    __syncthreads();
    if (tid<256){
      int b=tid>>6,k=tid&63;
      float ig=gl[b][k],fg=gl[b][64+k],gg=gl[b][128+k],og=gl[b][192+k];
      float c=sigmf(fg)*c1s[b][k]+sigmf(ig)*tanhfast(gg);
      c1s[b][k]=c; h1s[b][k]=sigmf(og)*tanhfast(c);
    }
    __syncthreads();
    // cell2 gates
    #pragma unroll
    for (int u=0;u<2;u++){
      const int b=half*2+u;
      float a0=bias2, a1=0.f, a2=0.f, a3=0.f;
      const float4* av=(const float4*)h1s[b];
      const float4* bv=(const float4*)h2s[b];
      #pragma unroll
      for (int c=0;c<16;c++){
        float4 q=av[c],p=bv[c];
        a0 = fmaf(q.x, w2ih[4*c+0], a0);
        a1 = fmaf(q.y, w2ih[4*c+1], a1);
        a2 = fmaf(q.z, w2ih[4*c+2], a2);
        a3 = fmaf(q.w, w2ih[4*c+3], a3);
        a0 = fmaf(p.x, w2hh[4*c+0], a0);
        a1 = fmaf(p.y, w2hh[4*c+1], a1);
        a2 = fmaf(p.z, w2hh[4*c+2], a2);
        a3 = fmaf(p.w, w2hh[4*c+3], a3);
      }
      gl[b][r]=(a0+a1)+(a2+a3);
    }
    __syncthreads();
    if (tid<256){
      int b=tid>>6,k=tid&63;
      float ig=gl[b][k],fg=gl[b][64+k],gg=gl[b][128+k],og=gl[b][192+k];
      float c=sigmf(fg)*c2s[b][k]+sigmf(ig)*tanhfast(gg);
      c2s[b][k]=c; h2s[b][k]=sigmf(og)*tanhfast(c);
    }
    __syncthreads();
    // classifier + output store
    if (tid < 4*VOC){
      int b=tid/VOC, v=tid-b*VOC;
      float a0=clsb_s[v], a1=0.f, a2=0.f, a3=0.f;
      const float4* hv=(const float4*)h2s[b];
      #pragma unroll
      for (int c=0;c<16;c++){
        float4 q=hv[c];
        a0 = fmaf(q.x, clsW_s[v][4*c+0], a0);
        a1 = fmaf(q.y, clsW_s[v][4*c+1], a1);
        a2 = fmaf(q.z, clsW_s[v][4*c+2], a2);
        a3 = fmaf(q.w, clsW_s[v][4*c+3], a3);
      }
      float p=(a0+a1)+(a2+a3);
      pred_s[b][v]=p;
      out[((size_t)s*BATCH + (size_t)(b0+b))*VOC + v]=p;
    }
    __syncthreads();
    // per-row argmax (first-index tie-break), one wave per row
    if (tid<256){
      int w=tid>>6, lane=tid&63;
      float v = (lane<VOC)? pred_s[w][lane] : -INFINITY;
      int ix = lane;
      #pragma unroll
      for (int off=32; off>0; off>>=1){
        float ov=__shfl_down(v,off);
        int oi=__shfl_down(ix,off);
        if (ov>v || (ov==v && oi<ix)){ v=ov; ix=oi; }
      }
      if (lane==0) atomicOr(&bm, 1u<<ix);
    }
    __syncthreads();
    // global union-mask barrier: one 64b fetch_or carries mask + arrival bit
    if (s+1<TSTEPS){
      if (tid==0){
        unsigned mb = bm;
        bool have=false; unsigned fm=0;
        unsigned long long v1 = (unsigned long long)mb | (1ULL << (32+idx));
        unsigned long long u1 = __hip_atomic_fetch_or(&lvl1[s*16 + grp*4], v1,
                                  __ATOMIC_RELAXED, __HIP_MEMORY_SCOPE_AGENT) | v1;
        if ((unsigned)(u1>>32) == 0xFFFFFFFFu){
          // last arrival in group: push group union up
          unsigned long long v2 = (u1 & 0x1FFFFFFFULL) | (1ULL << (32+grp));
          unsigned long long u2 = __hip_atomic_fetch_or(&lvl2[s*4], v2,
                                    __ATOMIC_RELAXED, __HIP_MEMORY_SCOPE_AGENT) | v2;
          if ((u2>>32) == 0xFULL){
            fm = (unsigned)u2 & 0x1FFFFFFFu;
            __hip_atomic_store(&bc[s*8], fm | 0x80000000u,
                               __ATOMIC_RELAXED, __HIP_MEMORY_SCOPE_AGENT);
            have=true;
          }
        }
        if (!have){
          unsigned c;
          do {
            __builtin_amdgcn_s_sleep(1);
            c = __hip_atomic_load(&bc[s*8], __ATOMIC_RELAXED, __HIP_MEMORY_SCOPE_AGENT);
          } while (!(c & 0x80000000u));
          fm = c & 0x1FFFFFFFu;
        }
        maskLDS = fm;
      }
      __syncthreads();
      mask = maskLDS;
    }
  }
}

extern "C" void kernel_launch(void* const* d_in, const int* in_sizes, int n_in,
                              void* d_out, int out_size, void* d_ws, size_t ws_size,
                              hipStream_t stream)
{
  const float* x     = (const float*)d_in[0];
  const float* eWih0 = (const float*)d_in[1];
  const float* eWhh0 = (const float*)d_in[2];
  const float* ebih0 = (const float*)d_in[3];
  const float* ebhh0 = (const float*)d_in[4];
  const float* eWih1 = (const float*)d_in[5];
  const float* eWhh1 = (const float*)d_in[6];
  const float* ebih1 = (const float*)d_in[7];
  const float* ebhh1 = (const float*)d_in[8];
  const float* d1Wih = (const float*)d_in[9];
  const float* d1Whh = (const float*)d_in[10];
  const float* d1bih = (const float*)d_in[11];
  const float* d1bhh = (const float*)d_in[12];
  const float* d2Wih = (const float*)d_in[13];
  const float* d2Whh = (const float*)d_in[14];
  const float* d2bih = (const float*)d_in[15];
  const float* d2bhh = (const float*)d_in[16];
  const float* clsW  = (const float*)d_in[17];
  const float* clsb  = (const float*)d_in[18];
  float* out = (float*)d_out;

  float* h1g = (float*)d_ws;
  float* c1g = h1g + BATCH*HID;
  char* barr = (char*)d_ws + (size_t)(2*BATCH*HID)*sizeof(float);     // 256 KB in
  unsigned long long* lvl1 = (unsigned long long*)barr;               // 1024*16 u64 = 128 KB
  unsigned long long* lvl2 = (unsigned long long*)(barr + 128*1024);  // 1024*4  u64 =  32 KB
  unsigned*           bcw  = (unsigned*)(barr + 160*1024);            // 1024*8  u32 =  32 KB

  hipMemsetAsync(barr, 0, 192*1024, stream);

  enc_kernel<<<ENC_BLOCKS, ENC_THREADS, 0, stream>>>(
      x, eWih0,eWhh0,ebih0,ebhh0, eWih1,eWhh1,ebih1,ebhh1, h1g,c1g);

  void* args[] = { (void*)&h1g, (void*)&c1g,
                   (void*)&d1Wih,(void*)&d1Whh,(void*)&d1bih,(void*)&d1bhh,
                   (void*)&d2Wih,(void*)&d2Whh,(void*)&d2bih,(void*)&d2bhh,
                   (void*)&clsW,(void*)&clsb,(void*)&out,
                   (void*)&lvl1,(void*)&lvl2,(void*)&bcw };
  hipLaunchCooperativeKernel((void*)dec_kernel, dim3(DEC_BLOCKS), dim3(DEC_THREADS),
                             args, 0, stream);
}

// Round 3
// 6677.392 us; speedup vs baseline: 1.9719x; 1.4397x over previous
//
#include <hip/hip_runtime.h>
#include <math.h>

#define TSTEPS 1024
#define BATCH  512
#define HID    64
#define VOC    29
#define G4     256
#define SOS    27
#define ENC_BLOCKS  256   // 2 batch rows per block
#define ENC_THREADS 512
#define DEC_BLOCKS  256   // 2 batch rows per block (cooperative, 1 block/CU)
#define DEC_THREADS 512
#define MASK29 0x1FFFFFFFULL

__device__ __forceinline__ float frcp(float x){ return __builtin_amdgcn_rcpf(x); }
__device__ __forceinline__ float sigmf(float x){ return frcp(1.0f + __expf(-x)); }
__device__ __forceinline__ float tanhfast(float x){ return 1.0f - 2.0f*frcp(1.0f + __expf(2.0f*x)); }

// ---------------- Encoder: 2-layer LSTM, 2 rows/block, half-row per thread ----------------
// thread t: r = t>>1 (gate row 0..255), p = t&1 (half). 96 weight floats/thread -> no spill.
__global__ __launch_bounds__(ENC_THREADS, 2)
void enc_kernel(const float* __restrict__ x,
                const float* __restrict__ Wih0, const float* __restrict__ Whh0,
                const float* __restrict__ bih0, const float* __restrict__ bhh0,
                const float* __restrict__ Wih1, const float* __restrict__ Whh1,
                const float* __restrict__ bih1, const float* __restrict__ bhh1,
                float* __restrict__ h1g, float* __restrict__ c1g)
{
  const int tid = threadIdx.x;
  const int r   = tid >> 1;
  const int p   = tid & 1;
  const int b0  = blockIdx.x * 2;

  __shared__ __align__(16) float w0s[G4][VOC];
  __shared__ __align__(16) float xs[2][32];
  __shared__ __align__(16) float g0[2][G4];
  __shared__ __align__(16) float h0s[2][HID], c0s[2][HID], h1s[2][HID], c1s[2][HID];

  for (int i = tid; i < G4*VOC; i += ENC_THREADS) ((float*)w0s)[i] = Wih0[i];

  float wh0[32], wi1[32], wh1[32];
  #pragma unroll
  for (int k=0;k<32;k++){
    wh0[k]=Whh0[r*HID+32*p+k];
    wi1[k]=Wih1[r*HID+32*p+k];
    wh1[k]=Whh1[r*HID+32*p+k];
  }
  const float bias0 = p ? 0.f : (bih0[r]+bhh0[r]);
  const float bias1 = p ? 0.f : (bih1[r]+bhh1[r]);

  if (tid<128){ int b=tid>>6,k=tid&63; h0s[b][k]=0.f;c0s[b][k]=0.f;h1s[b][k]=0.f;c1s[b][k]=0.f; }

  // prefetch threads: tid in [128,186)
  const int pi  = tid - 128;
  const int pb  = pi / VOC;          // 0/1
  const int pc  = pi - pb*VOC;
  const bool ispf = (pi >= 0) && (pi < 2*VOC);
  if (ispf) xs[pb][pc] = x[(size_t)(b0+pb)*VOC + pc];   // t = 0
  __syncthreads();

  for (int t=0;t<TSTEPS;t++){
    float xn = 0.f;
    if (ispf && t+1 < TSTEPS)
      xn = x[(size_t)(t+1)*BATCH*VOC + (size_t)(b0+pb)*VOC + pc];

    // layer0 gates: x-part (14 cols each half + col28 by p1) + h-part (32 each)
    const int cb = p*14;
    #pragma unroll
    for (int u=0;u<2;u++){
      float a0=bias0, a1=0.f, a2=0.f, a3=0.f;
      #pragma unroll
      for (int j=0;j<14;j+=2){
        a0 = fmaf(xs[u][cb+j],   w0s[r][cb+j],   a0);
        a1 = fmaf(xs[u][cb+j+1], w0s[r][cb+j+1], a1);
      }
      float xt = p ? xs[u][28] : 0.f;
      a2 = fmaf(xt, w0s[r][28], a2);
      const float4* hv = (const float4*)(h0s[u] + 32*p);
      #pragma unroll
      for (int c=0;c<8;c++){
        float4 q = hv[c];
        a0 = fmaf(q.x, wh0[4*c+0], a0);
        a1 = fmaf(q.y, wh0[4*c+1], a1);
        a2 = fmaf(q.z, wh0[4*c+2], a2);
        a3 = fmaf(q.w, wh0[4*c+3], a3);
      }
      float v=(a0+a1)+(a2+a3);
      v += __shfl_xor(v,1);
      g0[u][r]=v;
    }
    __syncthreads();
    if (tid<128){
      int b=tid>>6,k=tid&63;
      float ig=g0[b][k], fg=g0[b][64+k], gg=g0[b][128+k], og=g0[b][192+k];
      float c = sigmf(fg)*c0s[b][k] + sigmf(ig)*tanhfast(gg);
      c0s[b][k]=c;
      h0s[b][k]=sigmf(og)*tanhfast(c);
    }
    __syncthreads();
    // layer1 gates
    #pragma unroll
    for (int u=0;u<2;u++){
      float a0=bias1, a1=0.f, a2=0.f, a3=0.f;
      const float4* av = (const float4*)(h0s[u] + 32*p);
      const float4* bv = (const float4*)(h1s[u] + 32*p);
      #pragma unroll
      for (int c=0;c<8;c++){
        float4 q = av[c], w = bv[c];
        a0 = fmaf(q.x, wi1[4*c+0], a0);
        a1 = fmaf(q.y, wi1[4*c+1], a1);
        a2 = fmaf(q.z, wi1[4*c+2], a2);
        a3 = fmaf(q.w, wi1[4*c+3], a3);
        a0 = fmaf(w.x, wh1[4*c+0], a0);
        a1 = fmaf(w.y, wh1[4*c+1], a1);
        a2 = fmaf(w.z, wh1[4*c+2], a2);
        a3 = fmaf(w.w, wh1[4*c+3], a3);
      }
      float v=(a0+a1)+(a2+a3);
      v += __shfl_xor(v,1);
      g0[u][r]=v;
    }
    __syncthreads();
    if (tid<128){
      int b=tid>>6,k=tid&63;
      float ig=g0[b][k], fg=g0[b][64+k], gg=g0[b][128+k], og=g0[b][192+k];
      float c = sigmf(fg)*c1s[b][k] + sigmf(ig)*tanhfast(gg);
      c1s[b][k]=c;
      h1s[b][k]=sigmf(og)*tanhfast(c);
    } else if (ispf && t+1<TSTEPS){
      xs[pb][pc] = xn;          // prefetch store, consumed after the sync below
    }
    __syncthreads();
  }

  if (tid<128){
    int b=tid>>6,k=tid&63;
    h1g[(b0+b)*HID+k]=h1s[b][k];
    c1g[(b0+b)*HID+k]=c1s[b][k];
  }
}

// ---------------- Decoder: cooperative, 2 rows/block, half-row per thread ----------------
__global__ __launch_bounds__(DEC_THREADS, 2)
void dec_kernel(const float* __restrict__ h1gp, const float* __restrict__ c1gp,
                const float* __restrict__ W1ih, const float* __restrict__ W1hh,
                const float* __restrict__ b1ih, const float* __restrict__ b1hh,
                const float* __restrict__ W2ih, const float* __restrict__ W2hh,
                const float* __restrict__ b2ih, const float* __restrict__ b2hh,
                const float* __restrict__ clsW, const float* __restrict__ clsb,
                float* __restrict__ out,
                unsigned long long* __restrict__ lvl1,
                unsigned long long* __restrict__ lvl2,
                unsigned* __restrict__ bc)
{
  const int tid  = threadIdx.x;
  const int r    = tid >> 1;
  const int p    = tid & 1;
  const int b0   = blockIdx.x * 2;
  const unsigned grp = blockIdx.x & 7;   // XCD-aligned group (round-robin heuristic)
  const unsigned idx = blockIdx.x >> 3;  // 0..31 within group

  __shared__ __align__(16) float w1ih_s[G4][VOC];
  __shared__ __align__(16) float clsW_s[VOC][68];
  __shared__ __align__(16) float clsb_s[32];
  __shared__ __align__(16) float inp[G4];
  __shared__ __align__(16) float gl[2][G4];
  __shared__ __align__(16) float h1s[2][HID], c1s[2][HID], h2s[2][HID], c2s[2][HID];
  __shared__ __align__(16) float pred_s[2][32];
  __shared__ unsigned bm;
  __shared__ unsigned maskLDS;

  for (int i=tid;i<G4*VOC;i+=DEC_THREADS) ((float*)w1ih_s)[i] = W1ih[i];
  for (int i=tid;i<VOC*HID;i+=DEC_THREADS) clsW_s[i/HID][i%HID] = clsW[i];
  if (tid<VOC) clsb_s[tid]=clsb[tid];

  float w1h[32], w2i[32], w2h[32];
  #pragma unroll
  for (int k=0;k<32;k++){
    w1h[k]=W1hh[r*HID+32*p+k];
    w2i[k]=W2ih[r*HID+32*p+k];
    w2h[k]=W2hh[r*HID+32*p+k];
  }
  const float bias1v = (tid<G4)? (b1ih[tid]+b1hh[tid]) : 0.f;
  const float bias2  = p ? 0.f : (b2ih[r]+b2hh[r]);

  if (tid<128){
    int b=tid>>6,k=tid&63;
    h1s[b][k]=h1gp[(b0+b)*HID+k];
    c1s[b][k]=c1gp[(b0+b)*HID+k];
    h2s[b][k]=0.f; c2s[b][k]=0.f;
  }

  unsigned mask  = 1u<<SOS;
  unsigned built = 0xFFFFFFFFu;
  __syncthreads();

  for (int s=0;s<TSTEPS;s++){
    if (mask != built){           // block-uniform
      if (tid<G4){
        float vv = bias1v;
        #pragma unroll
        for (int c=0;c<VOC;c++)
          vv += (mask & (1u<<c)) ? w1ih_s[tid][c] : 0.f;
        inp[tid]=vv;
      }
      built = mask;
      __syncthreads();
    }
    if (tid==DEC_THREADS-1) bm = 0u;

    // cell1 gates (shared input term by p0, half h-dot each)
    #pragma unroll
    for (int u=0;u<2;u++){
      float a0 = p ? 0.f : inp[r];
      float a1=0.f, a2=0.f, a3=0.f;
      const float4* hv=(const float4*)(h1s[u] + 32*p);
      #pragma unroll
      for (int c=0;c<8;c++){
        float4 q=hv[c];
        a0 = fmaf(q.x, w1h[4*c+0], a0);
        a1 = fmaf(q.y, w1h[4*c+1], a1);
        a2 = fmaf(q.z, w1h[4*c+2], a2);
        a3 = fmaf(q.w, w1h[4*c+3], a3);
      }
      float v=(a0+a1)+(a2+a3);
      v += __shfl_xor(v,1);
      gl[u][r]=v;
    }
    __syncthreads();
    if (tid<128){
      int b=tid>>6,k=tid&63;
      float ig=gl[b][k],fg=gl[b][64+k],gg=gl[b][128+k],og=gl[b][192+k];
      float c=sigmf(fg)*c1s[b][k]+sigmf(ig)*tanhfast(gg);
      c1s[b][k]=c; h1s[b][k]=sigmf(og)*tanhfast(c);
    }
    __syncthreads();
    // cell2 gates
    #pragma unroll
    for (int u=0;u<2;u++){
      float a0=bias2, a1=0.f, a2=0.f, a3=0.f;
      const float4* av=(const float4*)(h1s[u] + 32*p);
      const float4* bv=(const float4*)(h2s[u] + 32*p);
      #pragma unroll
      for (int c=0;c<8;c++){
        float4 q=av[c], w=bv[c];
        a0 = fmaf(q.x, w2i[4*c+0], a0);
        a1 = fmaf(q.y, w2i[4*c+1], a1);
        a2 = fmaf(q.z, w2i[4*c+2], a2);
        a3 = fmaf(q.w, w2i[4*c+3], a3);
        a0 = fmaf(w.x, w2h[4*c+0], a0);
        a1 = fmaf(w.y, w2h[4*c+1], a1);
        a2 = fmaf(w.z, w2h[4*c+2], a2);
        a3 = fmaf(w.w, w2h[4*c+3], a3);
      }
      float v=(a0+a1)+(a2+a3);
      v += __shfl_xor(v,1);
      gl[u][r]=v;
    }
    __syncthreads();
    if (tid<128){
      int b=tid>>6,k=tid&63;
      float ig=gl[b][k],fg=gl[b][64+k],gg=gl[b][128+k],og=gl[b][192+k];
      float c=sigmf(fg)*c2s[b][k]+sigmf(ig)*tanhfast(gg);
      c2s[b][k]=c; h2s[b][k]=sigmf(og)*tanhfast(c);
    }
    __syncthreads();
    // classifier + output store
    if (tid < 2*VOC){
      int b=tid/VOC, v=tid-b*VOC;
      float a0=clsb_s[v], a1=0.f, a2=0.f, a3=0.f;
      const float4* hv=(const float4*)h2s[b];
      #pragma unroll
      for (int c=0;c<16;c++){
        float4 q=hv[c];
        a0 = fmaf(q.x, clsW_s[v][4*c+0], a0);
        a1 = fmaf(q.y, clsW_s[v][4*c+1], a1);
        a2 = fmaf(q.z, clsW_s[v][4*c+2], a2);
        a3 = fmaf(q.w, clsW_s[v][4*c+3], a3);
      }
      float pv=(a0+a1)+(a2+a3);
      pred_s[b][v]=pv;
      out[((size_t)s*BATCH + (size_t)(b0+b))*VOC + v]=pv;
    }
    __syncthreads();
    // per-row argmax (first-index tie-break), one wave per row
    if (tid<128){
      int w=tid>>6, lane=tid&63;
      float v = (lane<VOC)? pred_s[w][lane] : -INFINITY;
      int ix = lane;
      #pragma unroll
      for (int off=32; off>0; off>>=1){
        float ov=__shfl_down(v,off);
        int oi=__shfl_down(ix,off);
        if (ov>v || (ov==v && oi<ix)){ v=ov; ix=oi; }
      }
      if (lane==0) atomicOr(&bm, 1u<<ix);
    }
    __syncthreads();
    // global union-mask barrier: tree of 64b fetch_or carrying mask + arrival bits
    if (s+1<TSTEPS){
      if (tid==0){
        unsigned mb = bm;
        bool have=false; unsigned fm=0;
        unsigned long long v1 = (unsigned long long)mb | (1ULL << (32+idx));
        unsigned long long u1 = __hip_atomic_fetch_or(&lvl1[grp*TSTEPS + s], v1,
                                  __ATOMIC_RELAXED, __HIP_MEMORY_SCOPE_AGENT) | v1;
        if ((unsigned)(u1>>32) == 0xFFFFFFFFu){
          unsigned long long v2 = (u1 & MASK29) | (1ULL << (32+grp));
          unsigned long long u2 = __hip_atomic_fetch_or(&lvl2[s], v2,
                                    __ATOMIC_RELAXED, __HIP_MEMORY_SCOPE_AGENT) | v2;
          if ((u2>>32) == 0xFFULL){
            fm = (unsigned)(u2 & MASK29);
            __hip_atomic_store(&bc[s], fm | 0x80000000u,
                               __ATOMIC_RELAXED, __HIP_MEMORY_SCOPE_AGENT);
            have=true;
          }
        }
        if (!have){
          unsigned c;
          do {
            __builtin_amdgcn_s_sleep(1);
            c = __hip_atomic_load(&bc[s], __ATOMIC_RELAXED, __HIP_MEMORY_SCOPE_AGENT);
          } while (!(c & 0x80000000u));
          fm = c & 0x1FFFFFFFu;
        }
        maskLDS = fm;
      }
      __syncthreads();
      mask = maskLDS;
    }
  }
}

extern "C" void kernel_launch(void* const* d_in, const int* in_sizes, int n_in,
                              void* d_out, int out_size, void* d_ws, size_t ws_size,
                              hipStream_t stream)
{
  const float* x     = (const float*)d_in[0];
  const float* eWih0 = (const float*)d_in[1];
  const float* eWhh0 = (const float*)d_in[2];
  const float* ebih0 = (const float*)d_in[3];
  const float* ebhh0 = (const float*)d_in[4];
  const float* eWih1 = (const float*)d_in[5];
  const float* eWhh1 = (const float*)d_in[6];
  const float* ebih1 = (const float*)d_in[7];
  const float* ebhh1 = (const float*)d_in[8];
  const float* d1Wih = (const float*)d_in[9];
  const float* d1Whh = (const float*)d_in[10];
  const float* d1bih = (const float*)d_in[11];
  const float* d1bhh = (const float*)d_in[12];
  const float* d2Wih = (const float*)d_in[13];
  const float* d2Whh = (const float*)d_in[14];
  const float* d2bih = (const float*)d_in[15];
  const float* d2bhh = (const float*)d_in[16];
  const float* clsW  = (const float*)d_in[17];
  const float* clsb  = (const float*)d_in[18];
  float* out = (float*)d_out;

  float* h1g = (float*)d_ws;
  float* c1g = h1g + BATCH*HID;
  char* barr = (char*)d_ws + (size_t)(2*BATCH*HID)*sizeof(float);      // 256 KB in
  unsigned long long* lvl1 = (unsigned long long*)barr;                // 8 grp * 1024 u64 = 64 KB
  unsigned long long* lvl2 = (unsigned long long*)(barr + 64*1024);    // 1024 u64 = 8 KB
  unsigned*           bcw  = (unsigned*)(barr + 72*1024);              // 1024 u32 = 4 KB

  hipMemsetAsync(barr, 0, 76*1024, stream);

  enc_kernel<<<ENC_BLOCKS, ENC_THREADS, 0, stream>>>(
      x, eWih0,eWhh0,ebih0,ebhh0, eWih1,eWhh1,ebih1,ebhh1, h1g,c1g);

  void* args[] = { (void*)&h1g, (void*)&c1g,
                   (void*)&d1Wih,(void*)&d1Whh,(void*)&d1bih,(void*)&d1bhh,
                   (void*)&d2Wih,(void*)&d2Whh,(void*)&d2bih,(void*)&d2bhh,
                   (void*)&clsW,(void*)&clsb,(void*)&out,
                   (void*)&lvl1,(void*)&lvl2,(void*)&bcw };
  hipLaunchCooperativeKernel((void*)dec_kernel, dim3(DEC_BLOCKS), dim3(DEC_THREADS),
                             args, 0, stream);
}

// Round 4
// 5880.778 us; speedup vs baseline: 2.2390x; 1.1355x over previous
//
#include <hip/hip_runtime.h>
#include <math.h>

#define TSTEPS 1024
#define BATCH  512
#define HID    64
#define VOC    29
#define SOS    27
#define MASK29 0x1FFFFFFFu

#define ENC_BLOCKS 256
#define DEC_BLOCKS 256
#define NTHREADS   512

__device__ __forceinline__ float frcp(float x){ return __builtin_amdgcn_rcpf(x); }
__device__ __forceinline__ float sigmf(float x){ return frcp(1.0f + __expf(-x)); }
__device__ __forceinline__ float tanhfast(float x){ return 1.0f - 2.0f*frcp(1.0f + __expf(2.0f*x)); }

// ---------------- Encoder: cross-layer pipelined 2-layer LSTM, 2 rows/block ----------------
// Waves 0-3 (tid<256): layer0 for step t.  Waves 4-7: layer1 for step t-1.
__global__ __attribute__((amdgpu_flat_work_group_size(NTHREADS,NTHREADS), amdgpu_waves_per_eu(2,2)))
void enc_kernel(const float* __restrict__ x,
                const float* __restrict__ Wih0, const float* __restrict__ Whh0,
                const float* __restrict__ bih0, const float* __restrict__ bhh0,
                const float* __restrict__ Wih1, const float* __restrict__ Whh1,
                const float* __restrict__ bih1, const float* __restrict__ bhh1,
                float* __restrict__ h1g, float* __restrict__ c1g)
{
  const int tid = threadIdx.x;
  const int b0  = blockIdx.x * 2;
  const bool g0 = tid < 256;
  const int  r  = g0 ? tid : (tid-256);

  __shared__ __align__(16) float xs[2][32];
  __shared__ __align__(16) float h0s[2][HID], h1s[2][HID];
  __shared__ __align__(16) float gA[2][256], gB[2][256];

  // weights in registers (forced resident by waves_per_eu(2,2))
  float wh[64], w2[64];
  if (g0){
    #pragma unroll
    for (int k=0;k<64;k++) wh[k] = Whh0[r*64+k];
    #pragma unroll
    for (int k=0;k<29;k++) w2[k] = Wih0[r*29+k];
    #pragma unroll
    for (int k=29;k<64;k++) w2[k] = 0.f;
  } else {
    #pragma unroll
    for (int k=0;k<64;k++){ wh[k] = Whh1[r*64+k]; w2[k] = Wih1[r*64+k]; }
  }
  const float bias = g0 ? (bih0[r]+bhh0[r]) : (bih1[r]+bhh1[r]);

  float creg = 0.f;   // layer0 c for tid<128 ; layer1 c for tid 256..383
  if (tid < 128){ int u=tid>>6,k=tid&63; h0s[u][k]=0.f; h1s[u][k]=0.f; }

  const int pidx = tid - 448;
  const bool pf  = (pidx >= 0) && (pidx < 2*VOC);
  const int prow = pf ? (pidx/VOC) : 0;
  const int pcol = pf ? (pidx%VOC) : 0;
  if (pf) xs[prow][pcol] = x[(size_t)(b0+prow)*VOC + pcol];   // t=0
  __syncthreads();

  for (int t=0;t<=TSTEPS;t++){
    float xv = 0.f;
    if (pf && t+1 < TSTEPS)
      xv = x[(size_t)(t+1)*BATCH*VOC + (size_t)(b0+prow)*VOC + pcol];

    if (g0){
      if (t < TSTEPS){
        #pragma unroll
        for (int u=0;u<2;u++){
          float a0=bias,a1=0.f,a2=0.f,a3=0.f;
          const float4* xv4 = (const float4*)xs[u];
          #pragma unroll
          for (int c=0;c<7;c++){
            float4 q=xv4[c];
            a0=fmaf(q.x,w2[4*c+0],a0); a1=fmaf(q.y,w2[4*c+1],a1);
            a2=fmaf(q.z,w2[4*c+2],a2); a3=fmaf(q.w,w2[4*c+3],a3);
          }
          a0=fmaf(xs[u][28],w2[28],a0);
          const float4* h4=(const float4*)h0s[u];
          #pragma unroll
          for (int c=0;c<16;c++){
            float4 q=h4[c];
            a0=fmaf(q.x,wh[4*c+0],a0); a1=fmaf(q.y,wh[4*c+1],a1);
            a2=fmaf(q.z,wh[4*c+2],a2); a3=fmaf(q.w,wh[4*c+3],a3);
          }
          gA[u][r]=(a0+a1)+(a2+a3);
        }
      }
    } else {
      if (t >= 1){
        #pragma unroll
        for (int u=0;u<2;u++){
          float a0=bias,a1=0.f,a2=0.f,a3=0.f;
          const float4* i4=(const float4*)h0s[u];
          const float4* h4=(const float4*)h1s[u];
          #pragma unroll
          for (int c=0;c<16;c++){
            float4 q=i4[c], w=h4[c];
            a0=fmaf(q.x,w2[4*c+0],a0); a1=fmaf(q.y,w2[4*c+1],a1);
            a2=fmaf(q.z,w2[4*c+2],a2); a3=fmaf(q.w,w2[4*c+3],a3);
            a0=fmaf(w.x,wh[4*c+0],a0); a1=fmaf(w.y,wh[4*c+1],a1);
            a2=fmaf(w.z,wh[4*c+2],a2); a3=fmaf(w.w,wh[4*c+3],a3);
          }
          gB[u][r]=(a0+a1)+(a2+a3);
        }
      }
    }
    __syncthreads();
    if (tid < 128){
      if (t < TSTEPS){
        int u=tid>>6,k=tid&63;
        float ig=gA[u][k],fg=gA[u][64+k],gg=gA[u][128+k],og=gA[u][192+k];
        float c=sigmf(fg)*creg + sigmf(ig)*tanhfast(gg);
        creg=c; h0s[u][k]=sigmf(og)*tanhfast(c);
      }
    } else if (tid < 384){
      if (t >= 1){
        int tt=tid-256,u=tt>>6,k=tt&63;
        float ig=gB[u][k],fg=gB[u][64+k],gg=gB[u][128+k],og=gB[u][192+k];
        float c=sigmf(fg)*creg + sigmf(ig)*tanhfast(gg);
        creg=c; h1s[u][k]=sigmf(og)*tanhfast(c);
      }
    }
    if (pf && t+1 < TSTEPS) xs[prow][pcol] = xv;
    __syncthreads();
  }

  if (tid >= 256 && tid < 384){
    int tt=tid-256,u=tt>>6,k=tt&63;
    h1g[(b0+u)*HID+k]=h1s[u][k];
    c1g[(b0+u)*HID+k]=creg;
  }
}

// ---------------- Decoder: cooperative, flat 16x16 one-hop union barrier ----------------
__global__ __attribute__((amdgpu_flat_work_group_size(NTHREADS,NTHREADS), amdgpu_waves_per_eu(2,2)))
void dec_kernel(const float* __restrict__ h1gp, const float* __restrict__ c1gp,
                const float* __restrict__ W1ih, const float* __restrict__ W1hh,
                const float* __restrict__ b1ih, const float* __restrict__ b1hh,
                const float* __restrict__ W2ih, const float* __restrict__ W2hh,
                const float* __restrict__ b2ih, const float* __restrict__ b2hh,
                const float* __restrict__ clsW, const float* __restrict__ clsb,
                float* __restrict__ out,
                unsigned long long* __restrict__ lvl1)
{
  const int tid  = threadIdx.x;
  const int r    = tid >> 1;
  const int p    = tid & 1;
  const int b0   = blockIdx.x * 2;
  const unsigned grp = blockIdx.x & 15;   // 16 groups
  const unsigned idx = blockIdx.x >> 4;   // 0..15 within group

  __shared__ __align__(16) float clsW_s[VOC][68];
  __shared__ __align__(16) float clsb_s[32];
  __shared__ __align__(16) float gl[2][256];
  __shared__ __align__(16) float h1s[2][HID], h2s[2][HID];
  __shared__ unsigned maskLDS;

  for (int i=tid;i<VOC*HID;i+=NTHREADS) clsW_s[i/HID][i%HID] = clsW[i];
  if (tid<VOC) clsb_s[tid]=clsb[tid];

  // per-thread weight halves (forced resident)
  float w1h[32], w2i[32], w2h[32], wi1c[15];
  #pragma unroll
  for (int k=0;k<32;k++){
    w1h[k]=W1hh[r*HID+32*p+k];
    w2i[k]=W2ih[r*HID+32*p+k];
    w2h[k]=W2hh[r*HID+32*p+k];
  }
  const int cbase = p ? 15 : 0;
  const int cn    = p ? 14 : 15;
  #pragma unroll
  for (int j=0;j<15;j++) wi1c[j] = (j<cn) ? W1ih[r*VOC+cbase+j] : 0.f;
  const float biasg = p ? 0.f : (b1ih[r]+b1hh[r]);
  const float bias2 = p ? 0.f : (b2ih[r]+b2hh[r]);

  float c1reg=0.f, c2reg=0.f;
  if (tid<128){
    int u=tid>>6,k=tid&63;
    h1s[u][k]=h1gp[(b0+u)*HID+k];
    c1reg    =c1gp[(b0+u)*HID+k];
    h2s[u][k]=0.f;
  }
  __syncthreads();

  // initial hd1 partial: own half of W1hh . h1
  float hd1[2];
  #pragma unroll
  for (int u=0;u<2;u++){
    float a0=0.f,a1=0.f,a2=0.f,a3=0.f;
    const float4* h4=(const float4*)(h1s[u]+32*p);
    #pragma unroll
    for (int c=0;c<8;c++){
      float4 q=h4[c];
      a0=fmaf(q.x,w1h[4*c+0],a0); a1=fmaf(q.y,w1h[4*c+1],a1);
      a2=fmaf(q.z,w1h[4*c+2],a2); a3=fmaf(q.w,w1h[4*c+3],a3);
    }
    hd1[u]=(a0+a1)+(a2+a3);
  }

  unsigned mask = 1u<<SOS;

  for (int s=0;s<TSTEPS;s++){
    // gate1 = input-term(mask) + hd1 (precomputed)
    #pragma unroll
    for (int u=0;u<2;u++){
      float it = biasg;
      #pragma unroll
      for (int j=0;j<15;j++)
        it += ((mask>>(cbase+j))&1u) ? wi1c[j] : 0.f;
      float v = it + hd1[u];
      v += __shfl_xor(v,1);
      if (!p) gl[u][r] = v;
    }
    __syncthreads();
    if (tid<128){
      int u=tid>>6,k=tid&63;
      float ig=gl[u][k],fg=gl[u][64+k],gg=gl[u][128+k],og=gl[u][192+k];
      float c=sigmf(fg)*c1reg+sigmf(ig)*tanhfast(gg);
      c1reg=c; h1s[u][k]=sigmf(og)*tanhfast(c);
    }
    __syncthreads();
    // gate2
    #pragma unroll
    for (int u=0;u<2;u++){
      float a0=bias2,a1=0.f,a2=0.f,a3=0.f;
      const float4* i4=(const float4*)(h1s[u]+32*p);
      const float4* h4=(const float4*)(h2s[u]+32*p);
      #pragma unroll
      for (int c=0;c<8;c++){
        float4 q=i4[c], w=h4[c];
        a0=fmaf(q.x,w2i[4*c+0],a0); a1=fmaf(q.y,w2i[4*c+1],a1);
        a2=fmaf(q.z,w2i[4*c+2],a2); a3=fmaf(q.w,w2i[4*c+3],a3);
        a0=fmaf(w.x,w2h[4*c+0],a0); a1=fmaf(w.y,w2h[4*c+1],a1);
        a2=fmaf(w.z,w2h[4*c+2],a2); a3=fmaf(w.w,w2h[4*c+3],a3);
      }
      float v=(a0+a1)+(a2+a3);
      v += __shfl_xor(v,1);
      if (!p) gl[u][r]=v;
    }
    __syncthreads();
    if (tid<128){
      int u=tid>>6,k=tid&63;
      float ig=gl[u][k],fg=gl[u][64+k],gg=gl[u][128+k],og=gl[u][192+k];
      float c=sigmf(fg)*c2reg+sigmf(ig)*tanhfast(gg);
      c2reg=c; h2s[u][k]=sigmf(og)*tanhfast(c);
    }
    __syncthreads();
    // classifier + argmax + arrival RMW: entirely within wave 0
    if (tid<64){
      int row=tid>>5, v=tid&31;
      float pv = -INFINITY;
      if (v<VOC){
        float a0=clsb_s[v],a1=0.f,a2=0.f,a3=0.f;
        const float4* h4=(const float4*)h2s[row];
        #pragma unroll
        for (int c=0;c<16;c++){
          float4 q=h4[c];
          a0=fmaf(q.x,clsW_s[v][4*c+0],a0); a1=fmaf(q.y,clsW_s[v][4*c+1],a1);
          a2=fmaf(q.z,clsW_s[v][4*c+2],a2); a3=fmaf(q.w,clsW_s[v][4*c+3],a3);
        }
        pv=(a0+a1)+(a2+a3);
        out[((size_t)s*BATCH + (size_t)(b0+row))*VOC + v]=pv;
      }
      int ix=v;
      #pragma unroll
      for (int off=16; off>0; off>>=1){
        float ov=__shfl_xor(pv,off);
        int   oi=__shfl_xor(ix,off);
        if (ov>pv || (ov==pv && oi<ix)){ pv=ov; ix=oi; }
      }
      unsigned bit = 1u<<ix;
      unsigned mb  = bit | __shfl_xor(bit,32);
      if (tid==0 && s+1<TSTEPS)
        __hip_atomic_fetch_or(&lvl1[(size_t)grp*TSTEPS+s],
                              (unsigned long long)mb | (1ULL<<(32+idx)),
                              __ATOMIC_RELAXED, __HIP_MEMORY_SCOPE_AGENT);
    }
    if (s+1<TSTEPS){
      // hd1 for next step (all threads) — hides the barrier round trip
      #pragma unroll
      for (int u=0;u<2;u++){
        float a0=0.f,a1=0.f,a2=0.f,a3=0.f;
        const float4* h4=(const float4*)(h1s[u]+32*p);
        #pragma unroll
        for (int c=0;c<8;c++){
          float4 q=h4[c];
          a0=fmaf(q.x,w1h[4*c+0],a0); a1=fmaf(q.y,w1h[4*c+1],a1);
          a2=fmaf(q.z,w1h[4*c+2],a2); a3=fmaf(q.w,w1h[4*c+3],a3);
        }
        hd1[u]=(a0+a1)+(a2+a3);
      }
      // poll all 16 group words (lane-parallel), union via shuffles
      if (tid<64){
        while (true){
          unsigned long long u64 = 0;
          if (tid<16)
            u64 = __hip_atomic_load(&lvl1[(size_t)tid*TSTEPS+s],
                                    __ATOMIC_RELAXED, __HIP_MEMORY_SCOPE_AGENT);
          bool ok = (tid>=16) || ((unsigned)(u64>>32) == 0xFFFFu);
          if (__ballot(ok) == ~0ull){
            unsigned m = (tid<16) ? ((unsigned)u64 & MASK29) : 0u;
            m |= __shfl_xor(m,1); m |= __shfl_xor(m,2);
            m |= __shfl_xor(m,4); m |= __shfl_xor(m,8);
            if (tid==0) maskLDS = m;
            break;
          }
        }
      }
      __syncthreads();
      mask = maskLDS;
    }
  }
}

extern "C" void kernel_launch(void* const* d_in, const int* in_sizes, int n_in,
                              void* d_out, int out_size, void* d_ws, size_t ws_size,
                              hipStream_t stream)
{
  const float* x     = (const float*)d_in[0];
  const float* eWih0 = (const float*)d_in[1];
  const float* eWhh0 = (const float*)d_in[2];
  const float* ebih0 = (const float*)d_in[3];
  const float* ebhh0 = (const float*)d_in[4];
  const float* eWih1 = (const float*)d_in[5];
  const float* eWhh1 = (const float*)d_in[6];
  const float* ebih1 = (const float*)d_in[7];
  const float* ebhh1 = (const float*)d_in[8];
  const float* d1Wih = (const float*)d_in[9];
  const float* d1Whh = (const float*)d_in[10];
  const float* d1bih = (const float*)d_in[11];
  const float* d1bhh = (const float*)d_in[12];
  const float* d2Wih = (const float*)d_in[13];
  const float* d2Whh = (const float*)d_in[14];
  const float* d2bih = (const float*)d_in[15];
  const float* d2bhh = (const float*)d_in[16];
  const float* clsW  = (const float*)d_in[17];
  const float* clsb  = (const float*)d_in[18];
  float* out = (float*)d_out;

  float* h1g = (float*)d_ws;
  float* c1g = h1g + BATCH*HID;
  unsigned long long* lvl1 = (unsigned long long*)((char*)d_ws + (size_t)(2*BATCH*HID)*sizeof(float));

  hipMemsetAsync(lvl1, 0, 16*TSTEPS*sizeof(unsigned long long), stream);

  enc_kernel<<<ENC_BLOCKS, NTHREADS, 0, stream>>>(
      x, eWih0,eWhh0,ebih0,ebhh0, eWih1,eWhh1,ebih1,ebhh1, h1g,c1g);

  void* args[] = { (void*)&h1g, (void*)&c1g,
                   (void*)&d1Wih,(void*)&d1Whh,(void*)&d1bih,(void*)&d1bhh,
                   (void*)&d2Wih,(void*)&d2Whh,(void*)&d2bih,(void*)&d2bhh,
                   (void*)&clsW,(void*)&clsb,(void*)&out,(void*)&lvl1 };
  hipLaunchCooperativeKernel((void*)dec_kernel, dim3(DEC_BLOCKS), dim3(NTHREADS),
                             args, 0, stream);
}